// Round 3
// baseline (295.255 us; speedup 1.0000x reference)
//
#include <hip/hip_runtime.h>
#include <hip/hip_bf16.h>
#include <stdint.h>
#include <stddef.h>

#define NQ 384
#define NK 384

typedef __attribute__((ext_vector_type(4))) float float4_;
typedef __attribute__((ext_vector_type(8))) short short8;
typedef __attribute__((ext_vector_type(2))) unsigned int uint2_;

__device__ __forceinline__ short f2bf(float f) {
  union { float f; uint32_t u; } v; v.f = f;
  uint32_t u = v.u;
  uint32_t r = (u + 0x7fffu + ((u >> 16) & 1u)) >> 16;
  return (short)r;
}

__device__ __forceinline__ unsigned int pk2(float lo, float hi) {
  __hip_bfloat162 r = __float22bfloat162_rn(make_float2(lo, hi));
  union { __hip_bfloat162 b; unsigned int u; } u; u.b = r;
  return u.u;
}

// ---------------- prep0: weight combine + bias combine + frag pack ----------------
// blocks 0..15 : Wqc = Wq @ W1[0:64]     (16 rows each)
// blocks 16..31: Wkc = Wk @ W1[64:128]
// block 32     : c1 = bq@W1[0:64] + b1 ; c2 = bk@W1[64:128]
// block 33     : pack W1[128:192] and W2 into MFMA frag order (bf16)
__global__ __launch_bounds__(256) void prep0(
    const float* __restrict__ Wq, const float* __restrict__ Wk,
    const float* __restrict__ W1, const float* __restrict__ b1,
    const float* __restrict__ bq, const float* __restrict__ bk,
    const float* __restrict__ W2,
    float* __restrict__ Wqc, float* __restrict__ Wkc,
    float* __restrict__ c1, float* __restrict__ c2,
    short* __restrict__ W1dfrag, short* __restrict__ W2frag)
{
  int bid = blockIdx.x, t = threadIdx.x;
  if (bid < 32) {
    int side = bid >> 4;
    int r0 = (bid & 15) * 16;
    const float* W = side ? Wk : Wq;
    const float* W1s = W1 + side * 64 * 128;
    float* Wc = side ? Wkc : Wqc;
    __shared__ float sW[16][64];
    for (int j = t; j < 1024; j += 256) sW[j >> 6][j & 63] = W[(r0 + (j >> 6)) * 64 + (j & 63)];
    __syncthreads();
    int c = t & 127, rg = (t >> 7) * 8;
    float acc[8] = {0.f, 0.f, 0.f, 0.f, 0.f, 0.f, 0.f, 0.f};
    for (int k = 0; k < 64; ++k) {
      float wv = W1s[k * 128 + c];
      #pragma unroll
      for (int j = 0; j < 8; ++j) acc[j] += sW[rg + j][k] * wv;
    }
    for (int j = 0; j < 8; ++j) Wc[(r0 + rg + j) * 128 + c] = acc[j];
  } else if (bid == 32) {
    if (t < 256) {
      int c = t & 127, side = t >> 7;
      const float* bias = side ? bk : bq;
      const float* W1s = W1 + side * 64 * 128;
      float acc = side ? 0.f : b1[c];
      for (int k = 0; k < 64; ++k) acc += bias[k] * W1s[k * 128 + c];
      (side ? c2 : c1)[c] = acc;
    }
  } else {
    for (int idx = t; idx < 8192; idx += 256) {
      int fi = idx >> 9;
      int l  = (idx >> 3) & 63;
      int i  = idx & 7;
      { int n = fi >> 1, s = fi & 1;
        int d = s * 32 + ((l >> 4) << 3) + i;
        int f = n * 16 + (l & 15);
        W1dfrag[idx] = f2bf(W1[(128 + d) * 128 + f]); }
      { int n2 = fi >> 2, s2 = fi & 3;
        int k = s2 * 32 + ((l >> 4) << 3) + i;
        int o = n2 * 16 + (l & 15);
        W2frag[idx] = f2bf(W2[k * 64 + o]); }
    }
  }
}

// ---------------- prep1: A1 = q_inv@Wqc + c1 ; A2 = k_inv@Wkc + c2 ----------------
// 384 blocks x 256 thr; block = 8 rows x 128 cols, K=256
__global__ __launch_bounds__(256) void prep1(
    const float* __restrict__ q_inv, const float* __restrict__ k_inv,
    const float* __restrict__ Wqc, const float* __restrict__ Wkc,
    const float* __restrict__ c1, const float* __restrict__ c2,
    float* __restrict__ A1, float* __restrict__ A2)
{
  int bid = blockIdx.x, t = threadIdx.x;
  int row0 = bid * 8;
  int side = row0 >= 1536;
  int r0 = row0 - side * 1536;
  const float* inv = (side ? k_inv : q_inv) + (size_t)r0 * 256;
  const float* Wc  = side ? Wkc : Wqc;
  const float* cc  = side ? c2 : c1;
  float* A = (side ? A2 : A1) + (size_t)r0 * 128;

  __shared__ float sI[8][256];
  for (int j = t; j < 2048; j += 256) sI[j >> 8][j & 255] = inv[j];
  __syncthreads();

  int c = t & 127, rg = (t >> 7) * 4;
  float acc[4] = {0.f, 0.f, 0.f, 0.f};
  for (int k = 0; k < 256; ++k) {
    float wv = Wc[k * 128 + c];
    #pragma unroll
    for (int j = 0; j < 4; ++j) acc[j] += sI[rg + j][k] * wv;
  }
  float cv = cc[c];
  #pragma unroll
  for (int j = 0; j < 4; ++j) A[(size_t)(rg + j) * 128 + c] = acc[j] + cv;
}

// ---------------- main fused kernel (both GEMMs operand-swapped) ----------------
// block = (b, 16 q, 16 k) = 256 pairs; 8 waves; wave w owns qi in {2w, 2w+1}
// GEMM1': hT = W1dT(A) x DotT(B)  -> C/D: col=ki, rows=f (4 consecutive f / lane)
// GEMM2': outT = W2T(A) x hT(B)   -> C/D: col=ki, rows=o (4 consecutive o / lane)
__global__ __launch_bounds__(512) void main_kernel(
    const float* __restrict__ q_equi, const float* __restrict__ k_equi,
    const float* __restrict__ A1, const float* __restrict__ A2,
    const short* __restrict__ W1dfrag, const short* __restrict__ W2frag,
    const float* __restrict__ b2, float* __restrict__ out)
{
  int bid = blockIdx.x;
  int b = bid / 576;
  int rem = bid - b * 576;
  int tq = rem / 24, tk = rem - (rem / 24) * 24;
  int q0 = tq * 16, k0 = tk * 16;

  __shared__ __align__(16) char smem[32768];
  float* sQ = (float*)smem;                 // [3][16][68] fp32 (phase 1)
  float* sK = (float*)(smem + 13056);       // [3][16][68] fp32 (phase 1)
  // phase 2: per-wave h tile, wave w at smem + w*4096: [16 ki][128 f] bf16, XOR-swizzled

  int tid = threadIdx.x;
  int w = tid >> 6, l = tid & 63;
  int g = l >> 4, r16 = l & 15;

  // ---- stage equi tiles ----
  const float* qsrc = q_equi + ((size_t)(b * NQ + q0)) * 192;
  const float* ksrc = k_equi + ((size_t)(b * NK + k0)) * 192;
  for (int j = tid; j < 3072; j += 512) {
    int rr = j / 192, cd = j - rr * 192;
    int c = cd >> 6, d = cd & 63;
    int li = c * 1088 + rr * 68 + d;
    sQ[li] = qsrc[j];
    sK[li] = ksrc[j];
  }
  __syncthreads();

  // ---- dot-product B-fragments (lane: col=ki=r16, k = s*32 + g*8 + i) ----
  short8 afrag[2][2];
  #pragma unroll
  for (int s = 0; s < 2; ++s) {
    int d0 = s * 32 + g * 8;
    float4_ kva[3], kvb[3];
    #pragma unroll
    for (int c = 0; c < 3; ++c) {
      kva[c] = *(const float4_*)&sK[c * 1088 + r16 * 68 + d0];
      kvb[c] = *(const float4_*)&sK[c * 1088 + r16 * 68 + d0 + 4];
    }
    #pragma unroll
    for (int m = 0; m < 2; ++m) {
      int qi = 2 * w + m;
      float4_ qva[3], qvb[3];
      #pragma unroll
      for (int c = 0; c < 3; ++c) {
        qva[c] = *(const float4_*)&sQ[c * 1088 + qi * 68 + d0];
        qvb[c] = *(const float4_*)&sQ[c * 1088 + qi * 68 + d0 + 4];
      }
      float da[4], db[4];
      #pragma unroll
      for (int i = 0; i < 4; ++i) {
        da[i] = qva[0][i] * kva[0][i] + qva[1][i] * kva[1][i] + qva[2][i] * kva[2][i];
        db[i] = qvb[0][i] * kvb[0][i] + qvb[1][i] * kvb[1][i] + qvb[2][i] * kvb[2][i];
      }
      union { short8 s8; unsigned int u[4]; } au;
      au.u[0] = pk2(da[0], da[1]);
      au.u[1] = pk2(da[2], da[3]);
      au.u[2] = pk2(db[0], db[1]);
      au.u[3] = pk2(db[2], db[3]);
      afrag[m][s] = au.s8;
    }
  }
  __syncthreads();   // all waves done with sQ/sK; smem becomes per-wave h tiles

  char* hbase = smem + w * 4096;
  const float* A1p = A1 + ((size_t)(b * NQ + q0)) * 128;
  const float* A2p = A2 + ((size_t)(b * NK + k0)) * 128;

  float4_ b2v[4];
  #pragma unroll
  for (int ot = 0; ot < 4; ++ot)
    b2v[ot] = *(const float4_*)&b2[ot * 16 + g * 4];

  #pragma unroll
  for (int m = 0; m < 2; ++m) {
    int qi = 2 * w + m;

    // acc1[ft] rows = f = ft*16 + g*4 + rr, col = ki = r16
    float4_ acc1[8];
    #pragma unroll
    for (int ft = 0; ft < 8; ++ft) {
      float4_ a1v = *(const float4_*)&A1p[qi * 128 + ft * 16 + g * 4];
      float4_ a2v = *(const float4_*)&A2p[r16 * 128 + ft * 16 + g * 4];
      acc1[ft] = a1v + a2v;
    }

    // GEMM1': A = W1dT frag, B = dot frag
    #pragma unroll
    for (int ft = 0; ft < 8; ++ft) {
      #pragma unroll
      for (int s = 0; s < 2; ++s) {
        short8 wf = *(const short8*)&W1dfrag[(((ft * 2 + s) * 64) + l) * 8];
        acc1[ft] = __builtin_amdgcn_mfma_f32_16x16x32_bf16(wf, afrag[m][s], acc1[ft], 0, 0, 0);
      }
    }

    // silu -> packed bf16 -> wave-private LDS h[ki][f] (XOR swizzled)
    #pragma unroll
    for (int ft = 0; ft < 8; ++ft) {
      float4_ x = acc1[ft];
      float y0 = x[0] / (1.f + __expf(-x[0]));
      float y1 = x[1] / (1.f + __expf(-x[1]));
      float y2 = x[2] / (1.f + __expf(-x[2]));
      float y3 = x[3] / (1.f + __expf(-x[3]));
      uint2_ pv;
      pv[0] = pk2(y0, y1);
      pv[1] = pk2(y2, y3);
      int byte = (r16 * 256 + ft * 32 + g * 8) ^ ((r16 & 7) << 4);
      *(uint2_*)(hbase + byte) = pv;
    }

    // GEMM2': A = W2T frag, B = h frag (read back b128, same swizzle)
    float4_ acc2[4];
    #pragma unroll
    for (int ot = 0; ot < 4; ++ot) acc2[ot] = (float4_){0.f, 0.f, 0.f, 0.f};
    #pragma unroll
    for (int s2 = 0; s2 < 4; ++s2) {
      int byte = (r16 * 256 + s2 * 64 + g * 16) ^ ((r16 & 7) << 4);
      short8 hb = *(const short8*)(hbase + byte);
      #pragma unroll
      for (int ot = 0; ot < 4; ++ot) {
        short8 wf = *(const short8*)&W2frag[(((ot * 4 + s2) * 64) + l) * 8];
        acc2[ot] = __builtin_amdgcn_mfma_f32_16x16x32_bf16(wf, hb, acc2[ot], 0, 0, 0);
      }
    }

    // epilogue: float4 stores, rows o = ot*16 + g*4 + rr, pair (qi, k0+r16)
    float* op = out + ((size_t)(b * NQ + q0 + qi) * NK + k0 + r16) * 64;
    #pragma unroll
    for (int ot = 0; ot < 4; ++ot) {
      float4_ o4 = acc2[ot] + b2v[ot];
      *(float4_*)(op + ot * 16 + g * 4) = o4;
    }
  }
}

extern "C" void kernel_launch(void* const* d_in, const int* in_sizes, int n_in,
                              void* d_out, int out_size, void* d_ws, size_t ws_size,
                              hipStream_t stream) {
  (void)in_sizes; (void)n_in; (void)out_size; (void)ws_size;
  const float* q_equi = (const float*)d_in[0];
  const float* q_inv  = (const float*)d_in[1];
  const float* k_equi = (const float*)d_in[2];
  const float* k_inv  = (const float*)d_in[3];
  const float* Wq = (const float*)d_in[4];
  const float* bq = (const float*)d_in[5];
  const float* Wk = (const float*)d_in[6];
  const float* bk = (const float*)d_in[7];
  const float* W1 = (const float*)d_in[8];
  const float* b1 = (const float*)d_in[9];
  const float* W2 = (const float*)d_in[10];
  const float* b2 = (const float*)d_in[11];
  float* out = (float*)d_out;

  char* ws = (char*)d_ws;
  float* A1      = (float*)(ws);                // 786432 B
  float* A2      = (float*)(ws + 786432);       // 786432 B
  short* W1dfrag = (short*)(ws + 1572864);      // 16384 B
  short* W2frag  = (short*)(ws + 1589248);      // 16384 B
  float* Wqc     = (float*)(ws + 1605632);      // 131072 B
  float* Wkc     = (float*)(ws + 1736704);      // 131072 B
  float* c1      = (float*)(ws + 1867776);      // 512 B
  float* c2      = (float*)(ws + 1868288);      // 512 B

  prep0<<<34, 256, 0, stream>>>(Wq, Wk, W1, b1, bq, bk, W2, Wqc, Wkc, c1, c2, W1dfrag, W2frag);
  prep1<<<384, 256, 0, stream>>>(q_inv, k_inv, Wqc, Wkc, c1, c2, A1, A2);
  main_kernel<<<2304, 512, 0, stream>>>(q_equi, k_equi, A1, A2, W1dfrag, W2frag, b2, out);
}